// Round 6
// baseline (616.376 us; speedup 1.0000x reference)
//
#include <hip/hip_runtime.h>
#include <hip/hip_bf16.h>

// GCN layer: out = relu( (D^-1/2 A D^-1/2) (x @ w) + b )
//
// R6 pipeline (no global atomics anywhere):
//   bhist    per-block LDS bucket histogram (bucket = row>>7)
//   bscan    per-bucket exclusive scan over blocks
//   btot     bucket_base scan
//   bscatter edges -> bucket-sorted bedge (LDS offsets only)
//   csrify   block/bucket: LDS count+scan -> rstart, dinv (deg fused);
//            scatter bucket edges to exact final CSR slots. Slots [s,e) are
//            a contiguous permutation -> every 64B line fully dirtied by one
//            block -> perfect L2 write merge. ~2KB LDS, full occupancy.
//   gemm     bf16 MFMA 128x256 tile (x read ONCE), dinv fused in epilogue
//   agg      R4's plain CSR agg (221us, 78% occ) — R5 proved attaching the
//            sort to the consumer costs occupancy + LDS conflicts (249us).
// agg gather is throughput-capped ~4 TB/s past-L2 (R2->R3: 2x MLP no-op);
// fp8 h fails the error budget (8x current 0.0078 absmax > 0.029).

#define DF   256   // D_FEAT == FILTERS == 256
#define RSH  7
#define RPB  128   // rows per bucket
#define CHUNK 8192 // edges per block in bhist/bscatter

typedef __attribute__((ext_vector_type(8))) short short8;  // 8 x bf16
typedef __attribute__((ext_vector_type(4))) float f32x4;

__device__ __forceinline__ unsigned short f2bf(float f) {
    unsigned int u = __float_as_uint(f);
    unsigned int r = (u + 0x7fffu + ((u >> 16) & 1u)) >> 16;  // RNE
    return (unsigned short)r;
}
__device__ __forceinline__ float bflo(unsigned int u) { return __uint_as_float(u << 16); }
__device__ __forceinline__ float bfhi(unsigned int u) { return __uint_as_float(u & 0xffff0000u); }

// A1: per-block bucket histogram (NB <= 1024)
__global__ __launch_bounds__(256) void bhist_kernel(const int* __restrict__ row,
                                                    int* __restrict__ blockhist, int NB, int E) {
    __shared__ int hist[1024];
    int t = threadIdx.x;
    for (int i = t; i < NB; i += 256) hist[i] = 0;
    __syncthreads();
    int base = blockIdx.x * CHUNK;
    int end = base + CHUNK; if (end > E) end = E;
    for (int i = base + t; i < end; i += 256)
        atomicAdd(&hist[row[i] >> RSH], 1);
    __syncthreads();
    for (int i = t; i < NB; i += 256)
        blockhist[(size_t)blockIdx.x * NB + i] = hist[i];
}

// A2: per bucket, exclusive scan over NBLK block counts (NBLK <= 512), in place.
__global__ __launch_bounds__(256) void bscan_kernel(int* __restrict__ blockhist,
                                                    int* __restrict__ buckettot, int NB, int NBLK) {
    __shared__ int ps[256];
    int b = blockIdx.x, t = threadIdx.x;
    int e0 = 2 * t, e1 = 2 * t + 1;
    int v0 = (e0 < NBLK) ? blockhist[(size_t)e0 * NB + b] : 0;
    int v1 = (e1 < NBLK) ? blockhist[(size_t)e1 * NB + b] : 0;
    int tsum = v0 + v1;
    ps[t] = tsum;
    __syncthreads();
    for (int off = 1; off < 256; off <<= 1) {
        int v = (t >= off) ? ps[t - off] : 0;
        __syncthreads();
        ps[t] += v;
        __syncthreads();
    }
    int pre = ps[t] - tsum;  // exclusive
    if (e0 < NBLK) blockhist[(size_t)e0 * NB + b] = pre;
    if (e1 < NBLK) blockhist[(size_t)e1 * NB + b] = pre + v0;
    if (t == 255) buckettot[b] = ps[255];
}

// A2b: single block, exclusive scan of buckettot -> bucket_base[0..NB]
__global__ __launch_bounds__(1024) void btot_kernel(const int* __restrict__ buckettot,
                                                    int* __restrict__ bucket_base, int NB) {
    __shared__ int ps[1024];
    int t = threadIdx.x;
    int v = (t < NB) ? buckettot[t] : 0;
    ps[t] = v;
    __syncthreads();
    for (int off = 1; off < 1024; off <<= 1) {
        int u = (t >= off) ? ps[t - off] : 0;
        __syncthreads();
        ps[t] += u;
        __syncthreads();
    }
    if (t < NB) bucket_base[t] = ps[t] - v;
    if (t == 1023) bucket_base[NB] = ps[1023];
}

// A3: scatter edges into bucket-sorted bedge; LDS offsets only.
__global__ __launch_bounds__(256) void bscatter_kernel(const int* __restrict__ row,
                                                       const int* __restrict__ col,
                                                       const float* __restrict__ vals,
                                                       const int* __restrict__ blockhist,
                                                       const int* __restrict__ bucket_base,
                                                       int2* __restrict__ bedge, int NB, int E) {
    __shared__ int loff[1024];
    int t = threadIdx.x, blk = blockIdx.x;
    for (int i = t; i < NB; i += 256)
        loff[i] = bucket_base[i] + blockhist[(size_t)blk * NB + i];
    __syncthreads();
    int base = blk * CHUNK;
    int end = base + CHUNK; if (end > E) end = E;
    for (int i = base + t; i < end; i += 256) {
        int r = row[i];
        int p = atomicAdd(&loff[r >> RSH], 1);
        bedge[p] = make_int2(((r & (RPB - 1)) << 17) | col[i], __float_as_int(vals[i]));
    }
}

// csrify: block per bucket. LDS count+scan -> rstart/dinv; scatter to exact
// final CSR slots (contiguous permutation of [s,e) -> full L2 write merge).
__global__ __launch_bounds__(256) void csrify_kernel(const int2* __restrict__ bedge,
                                                     const int* __restrict__ bucket_base,
                                                     int2* __restrict__ scv,
                                                     int* __restrict__ rstart,
                                                     float* __restrict__ dinv, int N, int NB) {
    __shared__ int cnt[RPB];
    __shared__ float dacc[RPB];
    __shared__ int lrs[RPB + 1];
    __shared__ int lfill[RPB];
    int b = blockIdx.x, t = threadIdx.x;
    int s = bucket_base[b], e = bucket_base[b + 1];
    if (t < RPB) { cnt[t] = 0; dacc[t] = 0.f; lfill[t] = 0; }
    __syncthreads();
    for (int i = s + t; i < e; i += 256) {
        int2 ed = bedge[i];
        int rl = ed.x >> 17;
        atomicAdd(&cnt[rl], 1);
        atomicAdd(&dacc[rl], __int_as_float(ed.y));
    }
    __syncthreads();
    int myc = 0;
    if (t < RPB) { myc = cnt[t]; lrs[t] = myc; }
    __syncthreads();
    for (int off = 1; off < RPB; off <<= 1) {
        int v = (t < RPB && t >= off) ? lrs[t - off] : 0;
        __syncthreads();
        if (t < RPB) lrs[t] += v;
        __syncthreads();
    }
    if (t < RPB) {
        int iv = lrs[t];
        lrs[t] = iv - myc;                 // exclusive
        if (t == RPB - 1) lrs[RPB] = iv;
    }
    __syncthreads();
    if (t < RPB) {
        int r = b * RPB + t;
        if (r < N) {
            rstart[r] = s + lrs[t];
            float d = dacc[t];
            dinv[r] = (d > 0.f) ? (1.0f / sqrtf(d)) : 0.f;
        }
    }
    if (b == NB - 1 && t == 0) rstart[N] = e;
    for (int i = s + t; i < e; i += 256) {
        int2 ed = bedge[i];
        int rl = ed.x >> 17;
        int p = s + lrs[rl] + atomicAdd(&lfill[rl], 1);
        scv[p] = make_int2(ed.x & 0x1FFFF, ed.y);
    }
}

// w[256][256] fp32 -> wbf[256][256] bf16 TRANSPOSED (one-time, 128 KB out)
__global__ __launch_bounds__(256) void transpose_kernel(const float* __restrict__ w,
                                                        unsigned short* __restrict__ wbf) {
    __shared__ float tile[32][33];
    int bx = blockIdx.x * 32, by = blockIdx.y * 32;
    int tx = threadIdx.x, ty = threadIdx.y;  // dim(32,8)
    for (int j = ty; j < 32; j += 8) tile[j][tx] = w[(by + j) * DF + bx + tx];
    __syncthreads();
    for (int j = ty; j < 32; j += 8) wbf[(bx + j) * DF + by + tx] = f2bf(tile[tx][j]);
}

// MFMA bf16 GEMM: h'[r,:] = bf16( dinv[r] * (x[r,:] @ w) )
// 128x256 tile (x read once), BK=32, 4 waves in 2x2, wave = 64x128 = 4x8 MFMA.
__global__ __launch_bounds__(256) void gemm_kernel(const float* __restrict__ x,
                                                   const unsigned short* __restrict__ wbf,
                                                   const float* __restrict__ dinv,
                                                   unsigned short* __restrict__ h, int N) {
    __shared__ unsigned short Al[128 * 32];   // 8 KB
    __shared__ unsigned short Bl[256 * 32];   // 16 KB
    int tid = threadIdx.x;
    int by = blockIdx.x;
    int wv = tid >> 6, lane = tid & 63;
    int wr = wv >> 1, wc = wv & 1;
    int q = lane >> 4, mi = lane & 15;

    f32x4 acc[4][8];
#pragma unroll
    for (int i = 0; i < 4; ++i)
#pragma unroll
        for (int j = 0; j < 8; ++j) acc[i][j] = (f32x4){0.f, 0.f, 0.f, 0.f};

    int srow = tid >> 1;           // 0..127
    int sseg = (tid & 1) * 16;     // k offset 0 or 16
    int axrow = by * 128 + srow; if (axrow >= N) axrow = N - 1;
    const float* ax = x + (long)axrow * DF + sseg;
    const unsigned short* bx = wbf + (long)tid * DF;   // col = tid
    unsigned short* Aw = &Al[srow * 32 + sseg];
    unsigned short* Bw = &Bl[tid * 32];

    for (int kk = 0; kk < DF; kk += 32) {
        float4 a0 = *(const float4*)(ax + kk);
        float4 a1 = *(const float4*)(ax + kk + 4);
        float4 a2 = *(const float4*)(ax + kk + 8);
        float4 a3 = *(const float4*)(ax + kk + 12);
        const uint4* wp = (const uint4*)(bx + kk);
        uint4 b0 = wp[0], b1 = wp[1], b2 = wp[2], b3 = wp[3];
        __syncthreads();   // previous iteration's frag reads complete
        uint4 pa;
        pa.x = (unsigned)f2bf(a0.x) | ((unsigned)f2bf(a0.y) << 16);
        pa.y = (unsigned)f2bf(a0.z) | ((unsigned)f2bf(a0.w) << 16);
        pa.z = (unsigned)f2bf(a1.x) | ((unsigned)f2bf(a1.y) << 16);
        pa.w = (unsigned)f2bf(a1.z) | ((unsigned)f2bf(a1.w) << 16);
        *(uint4*)Aw = pa;
        pa.x = (unsigned)f2bf(a2.x) | ((unsigned)f2bf(a2.y) << 16);
        pa.y = (unsigned)f2bf(a2.z) | ((unsigned)f2bf(a2.w) << 16);
        pa.z = (unsigned)f2bf(a3.x) | ((unsigned)f2bf(a3.y) << 16);
        pa.w = (unsigned)f2bf(a3.z) | ((unsigned)f2bf(a3.w) << 16);
        *(uint4*)(Aw + 8) = pa;
        uint4* bw = (uint4*)Bw;
        bw[0] = b0; bw[1] = b1; bw[2] = b2; bw[3] = b3;
        __syncthreads();   // tiles ready

        short8 af[4], bf[8];
#pragma unroll
        for (int i = 0; i < 4; ++i)
            af[i] = *(const short8*)&Al[(wr * 64 + i * 16 + mi) * 32 + q * 8];
#pragma unroll
        for (int j = 0; j < 8; ++j)
            bf[j] = *(const short8*)&Bl[(wc * 128 + j * 16 + mi) * 32 + q * 8];
#pragma unroll
        for (int i = 0; i < 4; ++i)
#pragma unroll
            for (int j = 0; j < 8; ++j)
                acc[i][j] = __builtin_amdgcn_mfma_f32_16x16x32_bf16(af[i], bf[j], acc[i][j], 0, 0, 0);
    }

    // C/D layout: col = lane&15, row = (lane>>4)*4 + reg   [verified m89/m91]
#pragma unroll
    for (int i = 0; i < 4; ++i) {
        int base_row = by * 128 + wr * 64 + i * 16 + q * 4;
#pragma unroll
        for (int r = 0; r < 4; ++r) {
            int rg = base_row + r;
            if (rg < N) {
                float dv = dinv[rg];
#pragma unroll
                for (int j = 0; j < 8; ++j) {
                    int cg = wc * 128 + j * 16 + mi;
                    h[(long)rg * DF + cg] = f2bf(dv * acc[i][j][r]);
                }
            }
        }
    }
}

// One wave per node (R4 winner). Split-wave: lanes 0-31 even / 32-63 odd
// edges; lane owns 8 features via one uint4 load; unroll 4 -> 8 edges in
// flight; __shfl_xor(32) merge, coalesced float4 stores.
__global__ __launch_bounds__(256) void agg_kernel(const unsigned short* __restrict__ h,
                                                  const int* __restrict__ row_start,
                                                  const int2* __restrict__ scv,
                                                  const float* __restrict__ dinv,
                                                  const float* __restrict__ bias,
                                                  float* __restrict__ out, int N) {
    int wave = threadIdx.x >> 6;
    int lane = threadIdx.x & 63;
    int r = blockIdx.x * 4 + wave;
    if (r >= N) return;
    int half = lane >> 5;
    int fl = (lane & 31) * 8;
    int s = row_start[r], e = row_start[r + 1];
    float a0 = 0, a1 = 0, a2 = 0, a3 = 0, a4 = 0, a5 = 0, a6 = 0, a7 = 0;
    const unsigned short* hp = h + fl;
    int i = s + half;
    for (; i + 6 < e; i += 8) {
        int2 e0 = scv[i], e1 = scv[i + 2], e2 = scv[i + 4], e3 = scv[i + 6];
        uint4 u0 = *(const uint4*)(hp + (long)e0.x * DF);
        uint4 u1 = *(const uint4*)(hp + (long)e1.x * DF);
        uint4 u2 = *(const uint4*)(hp + (long)e2.x * DF);
        uint4 u3 = *(const uint4*)(hp + (long)e3.x * DF);
        float v0 = __int_as_float(e0.y), v1 = __int_as_float(e1.y);
        float v2 = __int_as_float(e2.y), v3 = __int_as_float(e3.y);
        a0 += v0 * bflo(u0.x) + v1 * bflo(u1.x) + v2 * bflo(u2.x) + v3 * bflo(u3.x);
        a1 += v0 * bfhi(u0.x) + v1 * bfhi(u1.x) + v2 * bfhi(u2.x) + v3 * bfhi(u3.x);
        a2 += v0 * bflo(u0.y) + v1 * bflo(u1.y) + v2 * bflo(u2.y) + v3 * bflo(u3.y);
        a3 += v0 * bfhi(u0.y) + v1 * bfhi(u1.y) + v2 * bfhi(u2.y) + v3 * bfhi(u3.y);
        a4 += v0 * bflo(u0.z) + v1 * bflo(u1.z) + v2 * bflo(u2.z) + v3 * bflo(u3.z);
        a5 += v0 * bfhi(u0.z) + v1 * bfhi(u1.z) + v2 * bfhi(u2.z) + v3 * bfhi(u3.z);
        a6 += v0 * bflo(u0.w) + v1 * bflo(u1.w) + v2 * bflo(u2.w) + v3 * bflo(u3.w);
        a7 += v0 * bfhi(u0.w) + v1 * bfhi(u1.w) + v2 * bfhi(u2.w) + v3 * bfhi(u3.w);
    }
    for (; i < e; i += 2) {
        int2 e0 = scv[i];
        float v0 = __int_as_float(e0.y);
        uint4 u0 = *(const uint4*)(hp + (long)e0.x * DF);
        a0 += v0 * bflo(u0.x); a1 += v0 * bfhi(u0.x);
        a2 += v0 * bflo(u0.y); a3 += v0 * bfhi(u0.y);
        a4 += v0 * bflo(u0.z); a5 += v0 * bfhi(u0.z);
        a6 += v0 * bflo(u0.w); a7 += v0 * bfhi(u0.w);
    }
    a0 += __shfl_xor(a0, 32); a1 += __shfl_xor(a1, 32);
    a2 += __shfl_xor(a2, 32); a3 += __shfl_xor(a3, 32);
    a4 += __shfl_xor(a4, 32); a5 += __shfl_xor(a5, 32);
    a6 += __shfl_xor(a6, 32); a7 += __shfl_xor(a7, 32);
    if (half == 0) {
        float dr = dinv[r];
        float4 b0 = *(const float4*)(bias + fl);
        float4 b1 = *(const float4*)(bias + fl + 4);
        float4 o0, o1;
        o0.x = fmaxf(fmaf(dr, a0, b0.x), 0.f);
        o0.y = fmaxf(fmaf(dr, a1, b0.y), 0.f);
        o0.z = fmaxf(fmaf(dr, a2, b0.z), 0.f);
        o0.w = fmaxf(fmaf(dr, a3, b0.w), 0.f);
        o1.x = fmaxf(fmaf(dr, a4, b1.x), 0.f);
        o1.y = fmaxf(fmaf(dr, a5, b1.y), 0.f);
        o1.z = fmaxf(fmaf(dr, a6, b1.z), 0.f);
        o1.w = fmaxf(fmaf(dr, a7, b1.w), 0.f);
        *(float4*)(out + (long)r * DF + fl) = o0;
        *(float4*)(out + (long)r * DF + fl + 4) = o1;
    }
}

extern "C" void kernel_launch(void* const* d_in, const int* in_sizes, int n_in,
                              void* d_out, int out_size, void* d_ws, size_t ws_size,
                              hipStream_t stream) {
    const float* x   = (const float*)d_in[0];
    const int* erow  = (const int*)d_in[1];
    const int* ecol  = (const int*)d_in[2];
    const float* ev  = (const float*)d_in[3];
    const float* w   = (const float*)d_in[4];
    const float* b   = (const float*)d_in[5];
    float* out = (float*)d_out;

    int N = in_sizes[0] / DF;
    int E = in_sizes[1];
    int NB = (N + RPB - 1) >> RSH;          // 782 (<=1024 supported)
    int NBLK = (E + CHUNK - 1) / CHUNK;     // 391 (<=512 supported)

    char* ws = (char*)d_ws;
    size_t Ea8 = (((size_t)E * 8) + 255) & ~(size_t)255;          // 25.6 MB
    size_t Hs  = (((size_t)N * DF * 2) + 255) & ~(size_t)255;     // 51.2 MB
    size_t Na  = (((size_t)N * 4) + 255) & ~(size_t)255;
    size_t RSa = (((size_t)(N + 1) * 4) + 255) & ~(size_t)255;

    // Layout (~77.7 MB; ≤ proven 78.6 MB high-water from R1):
    //   [0, Ea8)              scv          alive csrify -> agg
    //   [Ea8, Ea8+Hs)         h            alive gemm -> agg
    //     bedge aliases h[0, Ea8)          alive bscatter -> csrify (dead @ gemm)
    //     blockhist aliases h[Ea8, +1.3MB) alive bhist -> bscatter  (dead @ gemm)
    //   [Ea8+Hs, ...)         wbf, dinv, rstart, buckettot, bucket_base
    int2* scv = (int2*)ws;
    char* r2 = ws + Ea8;
    unsigned short* h = (unsigned short*)r2;
    int2* bedge = (int2*)r2;
    int* blockhist = (int*)(r2 + Ea8);
    char* r3 = r2 + Hs;
    unsigned short* wbf = (unsigned short*)r3;
    float* dinv = (float*)(r3 + 131072);
    int* rstart = (int*)(r3 + 131072 + Na);
    int* buckettot = (int*)(r3 + 131072 + Na + RSa);
    int* bucket_base = (int*)(r3 + 131072 + Na + RSa + 4096);

    bhist_kernel<<<NBLK, 256, 0, stream>>>(erow, blockhist, NB, E);
    bscan_kernel<<<NB, 256, 0, stream>>>(blockhist, buckettot, NB, NBLK);
    btot_kernel<<<1, 1024, 0, stream>>>(buckettot, bucket_base, NB);
    bscatter_kernel<<<NBLK, 256, 0, stream>>>(erow, ecol, ev, blockhist, bucket_base, bedge, NB, E);
    csrify_kernel<<<NB, 256, 0, stream>>>(bedge, bucket_base, scv, rstart, dinv, N, NB);
    transpose_kernel<<<dim3(8, 8), dim3(32, 8), 0, stream>>>(w, wbf);
    gemm_kernel<<<(N + 127) / 128, 256, 0, stream>>>(x, wbf, dinv, h, N);
    agg_kernel<<<(N + 3) / 4, 256, 0, stream>>>(h, rstart, scv, dinv, b, out, N);
}